// Round 1
// baseline (256.966 us; speedup 1.0000x reference)
//
#include <hip/hip_runtime.h>
#include <math.h>

// Problem constants
#define BATCH 8192
#define EMB 128
#define TILE 16          // rows per block
#define NTHREADS 256     // 4 waves
// LDS row strides (floats); all ≡ 4 mod 32 words -> conflict-benign, 16B aligned
#define XB_S 260
#define WIT_S 452
#define H_S 68
#define CODE_S 132

struct Smem {
    float XB[TILE][XB_S];     // base = [u_emb | v_emb], 256 cols
    float WIT[TILE][WIT_S];   // [w1(0:64) | w2(64:192) | w3(192:448)]
    float H[TILE][H_S];       // hidden scratch, 64 cols
    float CODE[TILE][CODE_S]; // tropical output, 128 cols
};

// Dense layer: OUT[r][o] = act( bias[o] + sum_k IN[r][k] * W[o][k] )
// Input may be two concatenated LDS segments (A of length KA, B of length KB).
// Each thread produces outputs o = osl + 16*i.  ACT: 0=relu, 1=sigmoid.
template <int KA, int KB, int O, int ACT>
__device__ __forceinline__ void dense_layer(
    const float* __restrict__ W, const float* __restrict__ bias,
    const float* inA, int sA,
    const float* inB, int sB,
    float* out, int sO, int r, int osl)
{
    constexpr int K = KA + KB;
    constexpr int TOT = O / 16;               // outputs per thread
    constexpr int NC = (TOT > 8) ? 8 : TOT;   // register-block chunk
    const float* xa = inA + r * sA;
    const float* xb = (KB > 0) ? (inB + r * sB) : nullptr;

    #pragma unroll
    for (int p = 0; p < TOT / NC; ++p) {
        const int o0 = osl + p * NC * 16;
        float acc[NC];
        #pragma unroll
        for (int i = 0; i < NC; ++i) acc[i] = bias[o0 + 16 * i];

        #pragma unroll 2
        for (int k = 0; k < KA; k += 4) {
            const float4 x = *(const float4*)(xa + k);
            #pragma unroll
            for (int i = 0; i < NC; ++i) {
                const float4 w = *(const float4*)(W + (size_t)(o0 + 16 * i) * K + k);
                acc[i] = fmaf(x.x, w.x, acc[i]);
                acc[i] = fmaf(x.y, w.y, acc[i]);
                acc[i] = fmaf(x.z, w.z, acc[i]);
                acc[i] = fmaf(x.w, w.w, acc[i]);
            }
        }
        if constexpr (KB > 0) {
            #pragma unroll 2
            for (int k = 0; k < KB; k += 4) {
                const float4 x = *(const float4*)(xb + k);
                #pragma unroll
                for (int i = 0; i < NC; ++i) {
                    const float4 w = *(const float4*)(W + (size_t)(o0 + 16 * i) * K + KA + k);
                    acc[i] = fmaf(x.x, w.x, acc[i]);
                    acc[i] = fmaf(x.y, w.y, acc[i]);
                    acc[i] = fmaf(x.z, w.z, acc[i]);
                    acc[i] = fmaf(x.w, w.w, acc[i]);
                }
            }
        }
        #pragma unroll
        for (int i = 0; i < NC; ++i) {
            float v = acc[i];
            if constexpr (ACT == 0) v = fmaxf(v, 0.0f);
            else                    v = 1.0f / (1.0f + __expf(-v));
            out[r * sO + o0 + 16 * i] = v;
        }
    }
}

// Tropical (min-plus): OUT[r][o] = min_j ( wit[r][j] + T[o][j] )
template <int K, int O>
__device__ __forceinline__ void tropical_layer(
    const float* __restrict__ T,
    const float* wit, int sW, float* out, int sO, int r, int osl)
{
    constexpr int NC = O / 16;  // 8
    float acc[NC];
    #pragma unroll
    for (int i = 0; i < NC; ++i) acc[i] = __builtin_inff();
    const float* x = wit + r * sW;

    #pragma unroll 2
    for (int k = 0; k < K; k += 4) {
        const float4 xv = *(const float4*)(x + k);
        #pragma unroll
        for (int i = 0; i < NC; ++i) {
            const float4 w = *(const float4*)(T + (size_t)(osl + 16 * i) * K + k);
            acc[i] = fminf(acc[i], xv.x + w.x);
            acc[i] = fminf(acc[i], xv.y + w.y);
            acc[i] = fminf(acc[i], xv.z + w.z);
            acc[i] = fminf(acc[i], xv.w + w.w);
        }
    }
    #pragma unroll
    for (int i = 0; i < NC; ++i) out[r * sO + osl + 16 * i] = acc[i];
}

__global__ __launch_bounds__(NTHREADS) void tacit_fused_kernel(
    const int* __restrict__ u, const int* __restrict__ v,
    const float* __restrict__ emb,
    const float* __restrict__ e1_w1, const float* __restrict__ e1_b1,
    const float* __restrict__ e1_w2, const float* __restrict__ e1_b2,
    const float* __restrict__ e2_w1, const float* __restrict__ e2_b1,
    const float* __restrict__ e2_w2, const float* __restrict__ e2_b2,
    const float* __restrict__ e3_w1, const float* __restrict__ e3_b1,
    const float* __restrict__ e3_w2, const float* __restrict__ e3_b2,
    const float* __restrict__ trop_w,
    const float* __restrict__ dec_w1, const float* __restrict__ dec_b1,
    const float* __restrict__ dec_w2, const float* __restrict__ dec_b2,
    float* __restrict__ out)
{
    __shared__ Smem S;
    const int tid = threadIdx.x;
    const int lane = tid & 63;
    const int wv = tid >> 6;
    const int r = lane & 15;                 // row within tile
    const int osl = wv * 4 + (lane >> 4);    // output slice 0..15
    const int row0 = blockIdx.x * TILE;

    // ---- Gather: XB[row] = [emb[u[row]] | emb[v[row]]] ----
    for (int idx = tid; idx < TILE * 64; idx += NTHREADS) {
        const int row = idx >> 6;
        const int c4 = idx & 63;                 // 64 float4 per row
        const int half = c4 >> 5;                // 0: u, 1: v
        const int col = (c4 & 31) * 4;
        const int node = half ? v[row0 + row] : u[row0 + row];
        const float4 val = *(const float4*)(emb + (size_t)node * EMB + col);
        *(float4*)(&S.XB[row][half * 128 + col]) = val;
    }
    __syncthreads();

    // ---- Witness extractor 1: base(256) -> H(64) relu -> w1(64) sigmoid ----
    dense_layer<256, 0, 64, 0>(e1_w1, e1_b1, &S.XB[0][0], XB_S, nullptr, 0,
                               &S.H[0][0], H_S, r, osl);
    __syncthreads();
    dense_layer<64, 0, 64, 1>(e1_w2, e1_b2, &S.H[0][0], H_S, nullptr, 0,
                              &S.WIT[0][0], WIT_S, r, osl);
    __syncthreads();

    // ---- Witness 2: [base|w1](320) -> H(64) relu -> w2(128) sigmoid ----
    dense_layer<256, 64, 64, 0>(e2_w1, e2_b1, &S.XB[0][0], XB_S, &S.WIT[0][0], WIT_S,
                                &S.H[0][0], H_S, r, osl);
    __syncthreads();
    dense_layer<64, 0, 128, 1>(e2_w2, e2_b2, &S.H[0][0], H_S, nullptr, 0,
                               &S.WIT[0][0] + 64, WIT_S, r, osl);
    __syncthreads();

    // ---- Witness 3: [base|w2](384) -> H(64) relu -> w3(256) sigmoid ----
    dense_layer<256, 128, 64, 0>(e3_w1, e3_b1, &S.XB[0][0], XB_S, &S.WIT[0][0] + 64, WIT_S,
                                 &S.H[0][0], H_S, r, osl);
    __syncthreads();
    dense_layer<64, 0, 256, 1>(e3_w2, e3_b2, &S.H[0][0], H_S, nullptr, 0,
                               &S.WIT[0][0] + 192, WIT_S, r, osl);
    __syncthreads();

    // ---- Tropical min-plus: WIT(448) x trop_w[128][448] -> CODE(128) ----
    tropical_layer<448, 128>(trop_w, &S.WIT[0][0], WIT_S, &S.CODE[0][0], CODE_S, r, osl);
    __syncthreads();

    // ---- Decoder layer 1: CODE(128) -> H(64) relu ----
    dense_layer<128, 0, 64, 0>(dec_w1, dec_b1, &S.CODE[0][0], CODE_S, nullptr, 0,
                               &S.H[0][0], H_S, r, osl);
    __syncthreads();

    // ---- Decoder layer 2: H(64) -> scalar ----
    if (tid < TILE) {
        float s = dec_b2[0];
        #pragma unroll
        for (int k = 0; k < 64; k += 4) {
            const float4 h4 = *(const float4*)(&S.H[tid][k]);
            const float4 w4 = *(const float4*)(dec_w2 + k);
            s = fmaf(h4.x, w4.x, s);
            s = fmaf(h4.y, w4.y, s);
            s = fmaf(h4.z, w4.z, s);
            s = fmaf(h4.w, w4.w, s);
        }
        out[row0 + tid] = s;
    }
}

extern "C" void kernel_launch(void* const* d_in, const int* in_sizes, int n_in,
                              void* d_out, int out_size, void* d_ws, size_t ws_size,
                              hipStream_t stream) {
    const int*   u      = (const int*)d_in[0];
    const int*   v      = (const int*)d_in[1];
    const float* emb    = (const float*)d_in[2];
    const float* e1_w1  = (const float*)d_in[3];
    const float* e1_b1  = (const float*)d_in[4];
    const float* e1_w2  = (const float*)d_in[5];
    const float* e1_b2  = (const float*)d_in[6];
    const float* e2_w1  = (const float*)d_in[7];
    const float* e2_b1  = (const float*)d_in[8];
    const float* e2_w2  = (const float*)d_in[9];
    const float* e2_b2  = (const float*)d_in[10];
    const float* e3_w1  = (const float*)d_in[11];
    const float* e3_b1  = (const float*)d_in[12];
    const float* e3_w2  = (const float*)d_in[13];
    const float* e3_b2  = (const float*)d_in[14];
    const float* trop_w = (const float*)d_in[15];
    const float* dec_w1 = (const float*)d_in[16];
    const float* dec_b1 = (const float*)d_in[17];
    const float* dec_w2 = (const float*)d_in[18];
    const float* dec_b2 = (const float*)d_in[19];
    float* out = (float*)d_out;

    dim3 grid(BATCH / TILE);   // 512 blocks
    dim3 block(NTHREADS);      // 256 threads
    tacit_fused_kernel<<<grid, block, 0, stream>>>(
        u, v, emb,
        e1_w1, e1_b1, e1_w2, e1_b2,
        e2_w1, e2_b1, e2_w2, e2_b2,
        e3_w1, e3_b1, e3_w2, e3_b2,
        trop_w, dec_w1, dec_b1, dec_w2, dec_b2,
        out);
}

// Round 3
// 190.568 us; speedup vs baseline: 1.3484x; 1.3484x over previous
//
#include <hip/hip_runtime.h>
#include <hip/hip_fp16.h>
#include <math.h>

#define BATCH 8192
#define EMB 128
#define TILE 16
#define NTHREADS 256

// LDS row strides in halves; all = 8*odd so row base is 16B-aligned and
// b128 reads across 16 rows hit 2 lanes/bank (free per m136).
#define XB_S 264   // 256 cols
#define WIT_S 456  // 448 cols
#define H_S 72     // 64 cols
#define CODE_S 136 // 128 cols

// fp16 weight layout in d_ws (element offsets):
#define OFF_E1W1 0        // 64x256
#define OFF_E1W2 16384    // 64x64
#define OFF_E2W1 20480    // 64x320
#define OFF_E2W2 40960    // 128x64
#define OFF_E3W1 49152    // 64x384
#define OFF_E3W2 73728    // 256x64
#define OFF_TROP 90112    // 128x448
#define OFF_DW1  147456   // 64x128
#define OFF_DW2  155648   // 1x64
#define W_TOTAL  155712

typedef __attribute__((ext_vector_type(2))) _Float16 half2v;

struct Smem {
    _Float16 XB[TILE][XB_S];
    _Float16 WIT[TILE][WIT_S];
    _Float16 H[TILE][H_S];
    _Float16 CODE[TILE][CODE_S];
};

// ---------------- weight fp32 -> fp16 pre-pass ----------------
__global__ __launch_bounds__(256) void cvt_weights_kernel(
    const float* __restrict__ s0, const float* __restrict__ s1,
    const float* __restrict__ s2, const float* __restrict__ s3,
    const float* __restrict__ s4, const float* __restrict__ s5,
    const float* __restrict__ s6, const float* __restrict__ s7,
    const float* __restrict__ s8, _Float16* __restrict__ ws)
{
    const int idx4 = (blockIdx.x * 256 + threadIdx.x) * 4;
    if (idx4 >= W_TOTAL) return;
    const float* src; int off;
    if      (idx4 < OFF_E1W2) { src = s0; off = OFF_E1W1; }
    else if (idx4 < OFF_E2W1) { src = s1; off = OFF_E1W2; }
    else if (idx4 < OFF_E2W2) { src = s2; off = OFF_E2W1; }
    else if (idx4 < OFF_E3W1) { src = s3; off = OFF_E2W2; }
    else if (idx4 < OFF_E3W2) { src = s4; off = OFF_E3W1; }
    else if (idx4 < OFF_TROP) { src = s5; off = OFF_E3W2; }
    else if (idx4 < OFF_DW1)  { src = s6; off = OFF_TROP; }
    else if (idx4 < OFF_DW2)  { src = s7; off = OFF_DW1;  }
    else                      { src = s8; off = OFF_DW2;  }
    const float4 v = *(const float4*)(src + (idx4 - off));
    _Float16* dst = ws + idx4;
    dst[0] = (_Float16)v.x;
    dst[1] = (_Float16)v.y;
    dst[2] = (_Float16)v.z;
    dst[3] = (_Float16)v.w;
}

// ---------------- fused forward ----------------
// Dense: OUT[r][o] = act(bias[o] + sum_k IN[r][k]*W[o][k]), fp16 in / fp32 acc.
// ACT: 0 = relu, 1 = sigmoid.
template <int KA, int KB, int O, int ACT>
__device__ __forceinline__ void dense16(
    const _Float16* __restrict__ W, const float* __restrict__ bias,
    const _Float16* inA, int sA, const _Float16* inB, int sB,
    _Float16* out, int sO, int r, int osl)
{
    constexpr int K = KA + KB;
    constexpr int TOT = O / 16;
    constexpr int NC = (TOT > 8) ? 8 : TOT;
    const _Float16* xa = inA + r * sA;
    const _Float16* xb = (KB > 0) ? (inB + r * sB) : nullptr;

    #pragma unroll
    for (int p = 0; p < TOT / NC; ++p) {
        const int o0 = osl + p * NC * 16;
        float acc[NC];
        #pragma unroll
        for (int i = 0; i < NC; ++i) acc[i] = bias[o0 + 16 * i];

        #pragma unroll 2
        for (int k = 0; k < KA; k += 8) {
            const float4 xr = *(const float4*)(xa + k);
            const half2v x0 = __builtin_bit_cast(half2v, xr.x);
            const half2v x1 = __builtin_bit_cast(half2v, xr.y);
            const half2v x2 = __builtin_bit_cast(half2v, xr.z);
            const half2v x3 = __builtin_bit_cast(half2v, xr.w);
            #pragma unroll
            for (int i = 0; i < NC; ++i) {
                const float4 wr = *(const float4*)(W + (size_t)(o0 + 16 * i) * K + k);
                acc[i] = __builtin_amdgcn_fdot2(x0, __builtin_bit_cast(half2v, wr.x), acc[i], false);
                acc[i] = __builtin_amdgcn_fdot2(x1, __builtin_bit_cast(half2v, wr.y), acc[i], false);
                acc[i] = __builtin_amdgcn_fdot2(x2, __builtin_bit_cast(half2v, wr.z), acc[i], false);
                acc[i] = __builtin_amdgcn_fdot2(x3, __builtin_bit_cast(half2v, wr.w), acc[i], false);
            }
        }
        if constexpr (KB > 0) {
            #pragma unroll 2
            for (int k = 0; k < KB; k += 8) {
                const float4 xr = *(const float4*)(xb + k);
                const half2v x0 = __builtin_bit_cast(half2v, xr.x);
                const half2v x1 = __builtin_bit_cast(half2v, xr.y);
                const half2v x2 = __builtin_bit_cast(half2v, xr.z);
                const half2v x3 = __builtin_bit_cast(half2v, xr.w);
                #pragma unroll
                for (int i = 0; i < NC; ++i) {
                    const float4 wr = *(const float4*)(W + (size_t)(o0 + 16 * i) * K + KA + k);
                    acc[i] = __builtin_amdgcn_fdot2(x0, __builtin_bit_cast(half2v, wr.x), acc[i], false);
                    acc[i] = __builtin_amdgcn_fdot2(x1, __builtin_bit_cast(half2v, wr.y), acc[i], false);
                    acc[i] = __builtin_amdgcn_fdot2(x2, __builtin_bit_cast(half2v, wr.z), acc[i], false);
                    acc[i] = __builtin_amdgcn_fdot2(x3, __builtin_bit_cast(half2v, wr.w), acc[i], false);
                }
            }
        }
        #pragma unroll
        for (int i = 0; i < NC; ++i) {
            float v = acc[i];
            if constexpr (ACT == 0) v = fmaxf(v, 0.0f);
            else                    v = 1.0f / (1.0f + __expf(-v));
            out[r * sO + o0 + 16 * i] = (_Float16)v;
        }
    }
}

// Tropical min-plus, packed fp16: OUT[r][o] = min_j(wit[r][j] + T[o][j])
// a+b on half2v -> v_pk_add_f16; __builtin_elementwise_min -> v_pk_min_f16.
template <int K, int O>
__device__ __forceinline__ void trop16(
    const _Float16* __restrict__ T,
    const _Float16* wit, int sW, _Float16* out, int sO, int r, int osl)
{
    constexpr int NC = O / 16;  // 8
    half2v acc[NC];
    const half2v big = { (_Float16)60000.0f, (_Float16)60000.0f };
    #pragma unroll
    for (int i = 0; i < NC; ++i) acc[i] = big;
    const _Float16* x = wit + r * sW;

    #pragma unroll 2
    for (int k = 0; k < K; k += 8) {
        const float4 xr = *(const float4*)(x + k);
        const half2v x0 = __builtin_bit_cast(half2v, xr.x);
        const half2v x1 = __builtin_bit_cast(half2v, xr.y);
        const half2v x2 = __builtin_bit_cast(half2v, xr.z);
        const half2v x3 = __builtin_bit_cast(half2v, xr.w);
        #pragma unroll
        for (int i = 0; i < NC; ++i) {
            const float4 wr = *(const float4*)(T + (size_t)(osl + 16 * i) * K + k);
            acc[i] = __builtin_elementwise_min(acc[i], x0 + __builtin_bit_cast(half2v, wr.x));
            acc[i] = __builtin_elementwise_min(acc[i], x1 + __builtin_bit_cast(half2v, wr.y));
            acc[i] = __builtin_elementwise_min(acc[i], x2 + __builtin_bit_cast(half2v, wr.z));
            acc[i] = __builtin_elementwise_min(acc[i], x3 + __builtin_bit_cast(half2v, wr.w));
        }
    }
    #pragma unroll
    for (int i = 0; i < NC; ++i) {
        const _Float16 lo = acc[i].x;
        const _Float16 hi = acc[i].y;
        out[r * sO + osl + 16 * i] = lo < hi ? lo : hi;
    }
}

__global__ __launch_bounds__(NTHREADS) void tacit_fused_kernel(
    const int* __restrict__ u, const int* __restrict__ v,
    const float* __restrict__ emb,
    const float* __restrict__ e1_b1, const float* __restrict__ e1_b2,
    const float* __restrict__ e2_b1, const float* __restrict__ e2_b2,
    const float* __restrict__ e3_b1, const float* __restrict__ e3_b2,
    const float* __restrict__ dec_b1, const float* __restrict__ dec_b2,
    const _Float16* __restrict__ ws,
    float* __restrict__ out)
{
    __shared__ Smem S;
    const int tid = threadIdx.x;
    const int lane = tid & 63;
    const int wv = tid >> 6;
    const int r = lane & 15;
    const int osl = wv * 4 + (lane >> 4);
    const int row0 = blockIdx.x * TILE;

    // ---- Gather + cvt: XB[row] = fp16([emb[u[row]] | emb[v[row]]]) ----
    for (int idx = tid; idx < TILE * 64; idx += NTHREADS) {
        const int row = idx >> 6;
        const int c4 = idx & 63;
        const int half_ = c4 >> 5;
        const int col = (c4 & 31) * 4;
        const int node = half_ ? v[row0 + row] : u[row0 + row];
        const float4 val = *(const float4*)(emb + (size_t)node * EMB + col);
        _Float16* dst = &S.XB[row][half_ * 128 + col];
        dst[0] = (_Float16)val.x;
        dst[1] = (_Float16)val.y;
        dst[2] = (_Float16)val.z;
        dst[3] = (_Float16)val.w;
    }
    __syncthreads();

    // ---- Witness 1: base(256) -> H(64) relu -> w1(64) sigmoid ----
    dense16<256, 0, 64, 0>(ws + OFF_E1W1, e1_b1, &S.XB[0][0], XB_S, nullptr, 0,
                           &S.H[0][0], H_S, r, osl);
    __syncthreads();
    dense16<64, 0, 64, 1>(ws + OFF_E1W2, e1_b2, &S.H[0][0], H_S, nullptr, 0,
                          &S.WIT[0][0], WIT_S, r, osl);
    __syncthreads();

    // ---- Witness 2: [base|w1](320) -> H(64) relu -> w2(128) sigmoid ----
    dense16<256, 64, 64, 0>(ws + OFF_E2W1, e2_b1, &S.XB[0][0], XB_S, &S.WIT[0][0], WIT_S,
                            &S.H[0][0], H_S, r, osl);
    __syncthreads();
    dense16<64, 0, 128, 1>(ws + OFF_E2W2, e2_b2, &S.H[0][0], H_S, nullptr, 0,
                           &S.WIT[0][0] + 64, WIT_S, r, osl);
    __syncthreads();

    // ---- Witness 3: [base|w2](384) -> H(64) relu -> w3(256) sigmoid ----
    dense16<256, 128, 64, 0>(ws + OFF_E3W1, e3_b1, &S.XB[0][0], XB_S, &S.WIT[0][0] + 64, WIT_S,
                             &S.H[0][0], H_S, r, osl);
    __syncthreads();
    dense16<64, 0, 256, 1>(ws + OFF_E3W2, e3_b2, &S.H[0][0], H_S, nullptr, 0,
                           &S.WIT[0][0] + 192, WIT_S, r, osl);
    __syncthreads();

    // ---- Tropical min-plus: WIT(448) x T[128][448] -> CODE(128) ----
    trop16<448, 128>(ws + OFF_TROP, &S.WIT[0][0], WIT_S, &S.CODE[0][0], CODE_S, r, osl);
    __syncthreads();

    // ---- Decoder 1: CODE(128) -> H(64) relu ----
    dense16<128, 0, 64, 0>(ws + OFF_DW1, dec_b1, &S.CODE[0][0], CODE_S, nullptr, 0,
                           &S.H[0][0], H_S, r, osl);
    __syncthreads();

    // ---- Decoder 2: H(64) -> scalar ----
    if (tid < TILE) {
        float s = dec_b2[0];
        const _Float16* h = &S.H[tid][0];
        const _Float16* w2 = ws + OFF_DW2;
        #pragma unroll
        for (int k = 0; k < 64; k += 8) {
            const float4 hr = *(const float4*)(h + k);
            const float4 wr = *(const float4*)(w2 + k);
            s = __builtin_amdgcn_fdot2(__builtin_bit_cast(half2v, hr.x), __builtin_bit_cast(half2v, wr.x), s, false);
            s = __builtin_amdgcn_fdot2(__builtin_bit_cast(half2v, hr.y), __builtin_bit_cast(half2v, wr.y), s, false);
            s = __builtin_amdgcn_fdot2(__builtin_bit_cast(half2v, hr.z), __builtin_bit_cast(half2v, wr.z), s, false);
            s = __builtin_amdgcn_fdot2(__builtin_bit_cast(half2v, hr.w), __builtin_bit_cast(half2v, wr.w), s, false);
        }
        out[row0 + tid] = s;
    }
}

extern "C" void kernel_launch(void* const* d_in, const int* in_sizes, int n_in,
                              void* d_out, int out_size, void* d_ws, size_t ws_size,
                              hipStream_t stream) {
    const int*   u      = (const int*)d_in[0];
    const int*   v      = (const int*)d_in[1];
    const float* emb    = (const float*)d_in[2];
    const float* e1_w1  = (const float*)d_in[3];
    const float* e1_b1  = (const float*)d_in[4];
    const float* e1_w2  = (const float*)d_in[5];
    const float* e1_b2  = (const float*)d_in[6];
    const float* e2_w1  = (const float*)d_in[7];
    const float* e2_b1  = (const float*)d_in[8];
    const float* e2_w2  = (const float*)d_in[9];
    const float* e2_b2  = (const float*)d_in[10];
    const float* e3_w1  = (const float*)d_in[11];
    const float* e3_b1  = (const float*)d_in[12];
    const float* e3_w2  = (const float*)d_in[13];
    const float* e3_b2  = (const float*)d_in[14];
    const float* trop_w = (const float*)d_in[15];
    const float* dec_w1 = (const float*)d_in[16];
    const float* dec_b1 = (const float*)d_in[17];
    const float* dec_w2 = (const float*)d_in[18];
    const float* dec_b2 = (const float*)d_in[19];
    float* out = (float*)d_out;
    _Float16* ws = (_Float16*)d_ws;

    const int cvt_blocks = (W_TOTAL / 4 + 255) / 256;  // 153
    cvt_weights_kernel<<<cvt_blocks, 256, 0, stream>>>(
        e1_w1, e1_w2, e2_w1, e2_w2, e3_w1, e3_w2, trop_w, dec_w1, dec_w2, ws);

    tacit_fused_kernel<<<BATCH / TILE, NTHREADS, 0, stream>>>(
        u, v, emb,
        e1_b1, e1_b2, e2_b1, e2_b2, e3_b1, e3_b2, dec_b1, dec_b2,
        ws, out);
}

// Round 4
// 189.235 us; speedup vs baseline: 1.3579x; 1.0070x over previous
//
#include <hip/hip_runtime.h>
#include <hip/hip_fp16.h>
#include <math.h>

#define BATCH 8192
#define EMB 128
#define TILE 16
#define NTHREADS 1024   // 16 waves; 2 blocks/CU -> 32 waves/CU (100% occupancy)

// LDS row strides in halves; all = 8*odd so row base is 16B-aligned and
// b128 reads across 16 rows hit 2 lanes/bank (free per m136).
#define XB_S 264   // 256 cols
#define WIT_S 456  // 448 cols
#define H_S 72     // 64 cols
#define CODE_S 136 // 128 cols

// fp16 weight layout in d_ws (element offsets):
#define OFF_E1W1 0        // 64x256
#define OFF_E1W2 16384    // 64x64
#define OFF_E2W1 20480    // 64x320
#define OFF_E2W2 40960    // 128x64
#define OFF_E3W1 49152    // 64x384
#define OFF_E3W2 73728    // 256x64
#define OFF_TROP 90112    // 128x448
#define OFF_DW1  147456   // 64x128
#define OFF_DW2  155648   // 1x64
#define W_TOTAL  155712

typedef __attribute__((ext_vector_type(2))) _Float16 half2v;

struct Smem {
    _Float16 XB[TILE][XB_S];
    _Float16 WIT[TILE][WIT_S];
    _Float16 H[TILE][H_S];
    _Float16 CODE[TILE][CODE_S];
};

// ---------------- weight fp32 -> fp16 pre-pass ----------------
__global__ __launch_bounds__(256) void cvt_weights_kernel(
    const float* __restrict__ s0, const float* __restrict__ s1,
    const float* __restrict__ s2, const float* __restrict__ s3,
    const float* __restrict__ s4, const float* __restrict__ s5,
    const float* __restrict__ s6, const float* __restrict__ s7,
    const float* __restrict__ s8, _Float16* __restrict__ ws)
{
    const int idx4 = (blockIdx.x * 256 + threadIdx.x) * 4;
    if (idx4 >= W_TOTAL) return;
    const float* src; int off;
    if      (idx4 < OFF_E1W2) { src = s0; off = OFF_E1W1; }
    else if (idx4 < OFF_E2W1) { src = s1; off = OFF_E1W2; }
    else if (idx4 < OFF_E2W2) { src = s2; off = OFF_E2W1; }
    else if (idx4 < OFF_E3W1) { src = s3; off = OFF_E2W2; }
    else if (idx4 < OFF_E3W2) { src = s4; off = OFF_E3W1; }
    else if (idx4 < OFF_TROP) { src = s5; off = OFF_E3W2; }
    else if (idx4 < OFF_DW1)  { src = s6; off = OFF_TROP; }
    else if (idx4 < OFF_DW2)  { src = s7; off = OFF_DW1;  }
    else                      { src = s8; off = OFF_DW2;  }
    const float4 v = *(const float4*)(src + (idx4 - off));
    _Float16* dst = ws + idx4;
    dst[0] = (_Float16)v.x;
    dst[1] = (_Float16)v.y;
    dst[2] = (_Float16)v.z;
    dst[3] = (_Float16)v.w;
}

// ---------------- fused forward ----------------
// Dense: OUT[r][o] = act(bias[o] + sum_k IN[r][k]*W[o][k]), fp16 in / fp32 acc.
// Thread covers outputs o = osl + 64*i, i < O/64.  ACT: 0 = relu, 1 = sigmoid.
template <int KA, int KB, int O, int ACT>
__device__ __forceinline__ void dense16(
    const _Float16* __restrict__ W, const float* __restrict__ bias,
    const _Float16* inA, int sA, const _Float16* inB, int sB,
    _Float16* out, int sO, int r, int osl)
{
    constexpr int K = KA + KB;
    constexpr int NC = O / 64;   // 1, 2, or 4
    const _Float16* xa = inA + r * sA;
    const _Float16* xb = (KB > 0) ? (inB + r * sB) : nullptr;

    float acc[NC];
    #pragma unroll
    for (int i = 0; i < NC; ++i) acc[i] = bias[osl + 64 * i];

    #pragma unroll 2
    for (int k = 0; k < KA; k += 8) {
        const float4 xr = *(const float4*)(xa + k);
        const half2v x0 = __builtin_bit_cast(half2v, xr.x);
        const half2v x1 = __builtin_bit_cast(half2v, xr.y);
        const half2v x2 = __builtin_bit_cast(half2v, xr.z);
        const half2v x3 = __builtin_bit_cast(half2v, xr.w);
        #pragma unroll
        for (int i = 0; i < NC; ++i) {
            const float4 wr = *(const float4*)(W + (size_t)(osl + 64 * i) * K + k);
            acc[i] = __builtin_amdgcn_fdot2(x0, __builtin_bit_cast(half2v, wr.x), acc[i], false);
            acc[i] = __builtin_amdgcn_fdot2(x1, __builtin_bit_cast(half2v, wr.y), acc[i], false);
            acc[i] = __builtin_amdgcn_fdot2(x2, __builtin_bit_cast(half2v, wr.z), acc[i], false);
            acc[i] = __builtin_amdgcn_fdot2(x3, __builtin_bit_cast(half2v, wr.w), acc[i], false);
        }
    }
    if constexpr (KB > 0) {
        #pragma unroll 2
        for (int k = 0; k < KB; k += 8) {
            const float4 xr = *(const float4*)(xb + k);
            const half2v x0 = __builtin_bit_cast(half2v, xr.x);
            const half2v x1 = __builtin_bit_cast(half2v, xr.y);
            const half2v x2 = __builtin_bit_cast(half2v, xr.z);
            const half2v x3 = __builtin_bit_cast(half2v, xr.w);
            #pragma unroll
            for (int i = 0; i < NC; ++i) {
                const float4 wr = *(const float4*)(W + (size_t)(osl + 64 * i) * K + KA + k);
                acc[i] = __builtin_amdgcn_fdot2(x0, __builtin_bit_cast(half2v, wr.x), acc[i], false);
                acc[i] = __builtin_amdgcn_fdot2(x1, __builtin_bit_cast(half2v, wr.y), acc[i], false);
                acc[i] = __builtin_amdgcn_fdot2(x2, __builtin_bit_cast(half2v, wr.z), acc[i], false);
                acc[i] = __builtin_amdgcn_fdot2(x3, __builtin_bit_cast(half2v, wr.w), acc[i], false);
            }
        }
    }
    #pragma unroll
    for (int i = 0; i < NC; ++i) {
        float v = acc[i];
        if constexpr (ACT == 0) v = fmaxf(v, 0.0f);
        else                    v = 1.0f / (1.0f + __expf(-v));
        out[r * sO + osl + 64 * i] = (_Float16)v;
    }
}

// Tropical min-plus, packed fp16: OUT[r][o] = min_j(wit[r][j] + T[o][j])
template <int K, int O>
__device__ __forceinline__ void trop16(
    const _Float16* __restrict__ T,
    const _Float16* wit, int sW, _Float16* out, int sO, int r, int osl)
{
    constexpr int NC = O / 64;  // 2
    half2v acc[NC];
    const half2v big = { (_Float16)60000.0f, (_Float16)60000.0f };
    #pragma unroll
    for (int i = 0; i < NC; ++i) acc[i] = big;
    const _Float16* x = wit + r * sW;

    #pragma unroll 2
    for (int k = 0; k < K; k += 8) {
        const float4 xr = *(const float4*)(x + k);
        const half2v x0 = __builtin_bit_cast(half2v, xr.x);
        const half2v x1 = __builtin_bit_cast(half2v, xr.y);
        const half2v x2 = __builtin_bit_cast(half2v, xr.z);
        const half2v x3 = __builtin_bit_cast(half2v, xr.w);
        #pragma unroll
        for (int i = 0; i < NC; ++i) {
            const float4 wr = *(const float4*)(T + (size_t)(osl + 64 * i) * K + k);
            acc[i] = __builtin_elementwise_min(acc[i], x0 + __builtin_bit_cast(half2v, wr.x));
            acc[i] = __builtin_elementwise_min(acc[i], x1 + __builtin_bit_cast(half2v, wr.y));
            acc[i] = __builtin_elementwise_min(acc[i], x2 + __builtin_bit_cast(half2v, wr.z));
            acc[i] = __builtin_elementwise_min(acc[i], x3 + __builtin_bit_cast(half2v, wr.w));
        }
    }
    #pragma unroll
    for (int i = 0; i < NC; ++i) {
        const _Float16 lo = acc[i].x;
        const _Float16 hi = acc[i].y;
        out[r * sO + osl + 64 * i] = lo < hi ? lo : hi;
    }
}

__global__ __launch_bounds__(NTHREADS) void tacit_fused_kernel(
    const int* __restrict__ u, const int* __restrict__ v,
    const float* __restrict__ emb,
    const float* __restrict__ e1_b1, const float* __restrict__ e1_b2,
    const float* __restrict__ e2_b1, const float* __restrict__ e2_b2,
    const float* __restrict__ e3_b1, const float* __restrict__ e3_b2,
    const float* __restrict__ dec_b1, const float* __restrict__ dec_b2,
    const _Float16* __restrict__ ws,
    float* __restrict__ out)
{
    __shared__ Smem S;
    const int tid = threadIdx.x;
    const int r = tid & 15;          // row within tile
    const int osl = tid >> 4;        // output slice 0..63
    const int row0 = blockIdx.x * TILE;

    // ---- Gather + cvt: XB[row] = fp16([emb[u[row]] | emb[v[row]]]) ----
    {
        const int idx = tid;                      // 1024 = 16 rows * 64 float4
        const int row = idx >> 6;
        const int c4 = idx & 63;
        const int half_ = c4 >> 5;
        const int col = (c4 & 31) * 4;
        const int node = half_ ? v[row0 + row] : u[row0 + row];
        const float4 val = *(const float4*)(emb + (size_t)node * EMB + col);
        _Float16* dst = &S.XB[row][half_ * 128 + col];
        dst[0] = (_Float16)val.x;
        dst[1] = (_Float16)val.y;
        dst[2] = (_Float16)val.z;
        dst[3] = (_Float16)val.w;
    }
    __syncthreads();

    // ---- Witness 1: base(256) -> H(64) relu -> w1(64) sigmoid ----
    dense16<256, 0, 64, 0>(ws + OFF_E1W1, e1_b1, &S.XB[0][0], XB_S, nullptr, 0,
                           &S.H[0][0], H_S, r, osl);
    __syncthreads();
    dense16<64, 0, 64, 1>(ws + OFF_E1W2, e1_b2, &S.H[0][0], H_S, nullptr, 0,
                          &S.WIT[0][0], WIT_S, r, osl);
    __syncthreads();

    // ---- Witness 2: [base|w1](320) -> H(64) relu -> w2(128) sigmoid ----
    dense16<256, 64, 64, 0>(ws + OFF_E2W1, e2_b1, &S.XB[0][0], XB_S, &S.WIT[0][0], WIT_S,
                            &S.H[0][0], H_S, r, osl);
    __syncthreads();
    dense16<64, 0, 128, 1>(ws + OFF_E2W2, e2_b2, &S.H[0][0], H_S, nullptr, 0,
                           &S.WIT[0][0] + 64, WIT_S, r, osl);
    __syncthreads();

    // ---- Witness 3: [base|w2](384) -> H(64) relu -> w3(256) sigmoid ----
    dense16<256, 128, 64, 0>(ws + OFF_E3W1, e3_b1, &S.XB[0][0], XB_S, &S.WIT[0][0] + 64, WIT_S,
                             &S.H[0][0], H_S, r, osl);
    __syncthreads();
    dense16<64, 0, 256, 1>(ws + OFF_E3W2, e3_b2, &S.H[0][0], H_S, nullptr, 0,
                           &S.WIT[0][0] + 192, WIT_S, r, osl);
    __syncthreads();

    // ---- Tropical min-plus: WIT(448) x T[128][448] -> CODE(128) ----
    trop16<448, 128>(ws + OFF_TROP, &S.WIT[0][0], WIT_S, &S.CODE[0][0], CODE_S, r, osl);
    __syncthreads();

    // ---- Decoder 1: CODE(128) -> H(64) relu ----
    dense16<128, 0, 64, 0>(ws + OFF_DW1, dec_b1, &S.CODE[0][0], CODE_S, nullptr, 0,
                           &S.H[0][0], H_S, r, osl);
    __syncthreads();

    // ---- Decoder 2: H(64) -> scalar ----
    if (tid < TILE) {
        float s = dec_b2[0];
        const _Float16* h = &S.H[tid][0];
        const _Float16* w2 = ws + OFF_DW2;
        #pragma unroll
        for (int k = 0; k < 64; k += 8) {
            const float4 hr = *(const float4*)(h + k);
            const float4 wr = *(const float4*)(w2 + k);
            s = __builtin_amdgcn_fdot2(__builtin_bit_cast(half2v, hr.x), __builtin_bit_cast(half2v, wr.x), s, false);
            s = __builtin_amdgcn_fdot2(__builtin_bit_cast(half2v, hr.y), __builtin_bit_cast(half2v, wr.y), s, false);
            s = __builtin_amdgcn_fdot2(__builtin_bit_cast(half2v, hr.z), __builtin_bit_cast(half2v, wr.z), s, false);
            s = __builtin_amdgcn_fdot2(__builtin_bit_cast(half2v, hr.w), __builtin_bit_cast(half2v, wr.w), s, false);
        }
        out[row0 + tid] = s;
    }
}

extern "C" void kernel_launch(void* const* d_in, const int* in_sizes, int n_in,
                              void* d_out, int out_size, void* d_ws, size_t ws_size,
                              hipStream_t stream) {
    const int*   u      = (const int*)d_in[0];
    const int*   v      = (const int*)d_in[1];
    const float* emb    = (const float*)d_in[2];
    const float* e1_w1  = (const float*)d_in[3];
    const float* e1_b1  = (const float*)d_in[4];
    const float* e1_w2  = (const float*)d_in[5];
    const float* e1_b2  = (const float*)d_in[6];
    const float* e2_w1  = (const float*)d_in[7];
    const float* e2_b1  = (const float*)d_in[8];
    const float* e2_w2  = (const float*)d_in[9];
    const float* e2_b2  = (const float*)d_in[10];
    const float* e3_w1  = (const float*)d_in[11];
    const float* e3_b1  = (const float*)d_in[12];
    const float* e3_w2  = (const float*)d_in[13];
    const float* e3_b2  = (const float*)d_in[14];
    const float* trop_w = (const float*)d_in[15];
    const float* dec_w1 = (const float*)d_in[16];
    const float* dec_b1 = (const float*)d_in[17];
    const float* dec_w2 = (const float*)d_in[18];
    const float* dec_b2 = (const float*)d_in[19];
    float* out = (float*)d_out;
    _Float16* ws = (_Float16*)d_ws;

    const int cvt_blocks = (W_TOTAL / 4 + 255) / 256;  // 153
    cvt_weights_kernel<<<cvt_blocks, 256, 0, stream>>>(
        e1_w1, e1_w2, e2_w1, e2_w2, e3_w1, e3_w2, trop_w, dec_w1, dec_w2, ws);

    tacit_fused_kernel<<<BATCH / TILE, NTHREADS, 0, stream>>>(
        u, v, emb,
        e1_b1, e1_b2, e2_b1, e2_b2, e3_b1, e3_b2, dec_b1, dec_b2,
        ws, out);
}

// Round 5
// 161.584 us; speedup vs baseline: 1.5903x; 1.1711x over previous
//
#include <hip/hip_runtime.h>
#include <hip/hip_fp16.h>
#include <math.h>

#define BATCH 8192
#define EMB 128
#define TILE 32          // rows per block
#define NTHREADS 1024    // 16 waves
#define NWAVES 16

// fp16 weight layout in d_ws (element offsets):
#define OFF_E1W1 0        // 64x256
#define OFF_E1W2 16384    // 64x64
#define OFF_E2W1 20480    // 64x320
#define OFF_E2W2 40960    // 128x64
#define OFF_E3W1 49152    // 64x384
#define OFF_E3W2 73728    // 256x64
#define OFF_TROP 90112    // 128x448
#define OFF_DW1  147456   // 64x128
#define OFF_DW2  155648   // 1x64
#define W_TOTAL  155712

typedef __attribute__((ext_vector_type(8))) _Float16 v8h;
typedef __attribute__((ext_vector_type(2))) _Float16 half2v;
typedef __attribute__((ext_vector_type(4))) float v4f;

// Chunked LDS activation layout: element (col k, row m) lives at
//   buf[((k>>3)*32 + m)*8 + (k&7)]
// so a 16B chunk is 8 contiguous k for one row — exactly an MFMA A-frag
// quad-slice and a b128 trop/x read.
struct Smem {
    _Float16 XB[32 * 32 * 8];   // 256 cols
    _Float16 WIT[56 * 32 * 8];  // 448 cols: w1 chunks 0-7, w2 8-23, w3 24-55
    _Float16 H[8 * 32 * 8];     // 64 cols
    _Float16 CODE[16 * 32 * 8]; // 128 cols
};  // 57,344 halves = 112 KB? no: *2B = 114,688 B... (actually 57,344*2 = 114,688? no: 28,672 elems? see static_assert below)

static_assert(sizeof(Smem) == (32*32*8 + 56*32*8 + 8*32*8 + 16*32*8) * 2, "lds size");

// ---------------- weight fp32 -> fp16 pre-pass ----------------
__global__ __launch_bounds__(256) void cvt_weights_kernel(
    const float* __restrict__ s0, const float* __restrict__ s1,
    const float* __restrict__ s2, const float* __restrict__ s3,
    const float* __restrict__ s4, const float* __restrict__ s5,
    const float* __restrict__ s6, const float* __restrict__ s7,
    const float* __restrict__ s8, _Float16* __restrict__ ws)
{
    const int idx4 = (blockIdx.x * 256 + threadIdx.x) * 4;
    if (idx4 >= W_TOTAL) return;
    const float* src; int off;
    if      (idx4 < OFF_E1W2) { src = s0; off = OFF_E1W1; }
    else if (idx4 < OFF_E2W1) { src = s1; off = OFF_E1W2; }
    else if (idx4 < OFF_E2W2) { src = s2; off = OFF_E2W1; }
    else if (idx4 < OFF_E3W1) { src = s3; off = OFF_E2W2; }
    else if (idx4 < OFF_E3W2) { src = s4; off = OFF_E3W1; }
    else if (idx4 < OFF_TROP) { src = s5; off = OFF_E3W2; }
    else if (idx4 < OFF_DW1)  { src = s6; off = OFF_TROP; }
    else if (idx4 < OFF_DW2)  { src = s7; off = OFF_DW1;  }
    else                      { src = s8; off = OFF_DW2;  }
    const float4 v = *(const float4*)(src + (idx4 - off));
    _Float16* dst = ws + idx4;
    dst[0] = (_Float16)v.x;
    dst[1] = (_Float16)v.y;
    dst[2] = (_Float16)v.z;
    dst[3] = (_Float16)v.w;
}

// ---------------- MFMA dense layer ----------------
// D[m][o] = act(bias[o] + sum_k A[m][k] * W[o][k]),  M = 32 rows, O outputs.
// A read from chunked LDS (A0 for k-steps < STEPS0, A1 after); W from global
// row-major [O][K] (= B^T input, lane n = lane&15 row, contiguous k — the
// m91/m92-verified pattern). Jobs = 2 Mtiles x (O/16) Ntiles over 16 waves;
// small layers run duplicated (identical benign writes).
template <int K, int STEPS0, int O, int ACT>
__device__ __forceinline__ void dense_mfma(
    const _Float16* __restrict__ Wg, const float* __restrict__ bias,
    const _Float16* A0, const _Float16* A1, _Float16* Out,
    int wave, int lane)
{
    constexpr int STEPS = K / 32;
    constexpr int NJOBS = 2 * (O / 16);
    constexpr int JLIM = (NJOBS < NWAVES) ? NWAVES : NJOBS;
    const int l15 = lane & 15;
    const int quad = lane >> 4;

    for (int job = wave; job < JLIM; job += NWAVES) {
        const int jid = job % NJOBS;
        const int mt = jid & 1;
        const int nt = jid >> 1;
        v4f c = {0.f, 0.f, 0.f, 0.f};
        const _Float16* wrow = Wg + (size_t)(nt * 16 + l15) * K + quad * 8;
        #pragma unroll
        for (int s = 0; s < STEPS; ++s) {
            const int g = s * 4 + quad;   // 8-col chunk index into A
            const _Float16* asrc = (s < STEPS0)
                ? (A0 + ((size_t)g * 32 + mt * 16 + l15) * 8)
                : (A1 + ((size_t)(g - STEPS0 * 4) * 32 + mt * 16 + l15) * 8);
            const v8h a = *(const v8h*)asrc;                 // A[m=l15][k=quad*8+j]
            const v8h b = *(const v8h*)(wrow + s * 32);      // B[n=l15][k=quad*8+j]
            c = __builtin_amdgcn_mfma_f32_16x16x32_f16(a, b, c, 0, 0, 0);
        }
        const int o = nt * 16 + l15;          // C/D: col = lane&15
        const float bs = bias[o];
        #pragma unroll
        for (int i = 0; i < 4; ++i) {         // C/D: row = quad*4 + reg
            float vv = c[i] + bs;
            if (ACT == 0) vv = fmaxf(vv, 0.f);
            else          vv = 1.f / (1.f + __expf(-vv));
            const int m = mt * 16 + quad * 4 + i;
            Out[((o >> 3) * 32 + m) * 8 + (o & 7)] = (_Float16)vv;
        }
    }
}

// ---------------- fused forward ----------------
__global__ __launch_bounds__(NTHREADS) void tacit_fused_kernel(
    const int* __restrict__ u, const int* __restrict__ v,
    const float* __restrict__ emb,
    const float* __restrict__ e1_b1, const float* __restrict__ e1_b2,
    const float* __restrict__ e2_b1, const float* __restrict__ e2_b2,
    const float* __restrict__ e3_b1, const float* __restrict__ e3_b2,
    const float* __restrict__ dec_b1, const float* __restrict__ dec_b2,
    const _Float16* __restrict__ ws,
    float* __restrict__ out)
{
    __shared__ Smem S;
    const int tid = threadIdx.x;
    const int lane = tid & 63;
    const int wave = tid >> 6;
    const int row0 = blockIdx.x * TILE;

    // ---- Gather + cvt into chunked XB ----
    {
        const int row = tid & 31;
        const int kq = tid >> 5;     // 0..31: chunks 0-15 = u-emb, 16-31 = v-emb
        const int node = (kq < 16) ? u[row0 + row] : v[row0 + row];
        const int col = (kq & 15) * 8;
        const float4 f0 = *(const float4*)(emb + (size_t)node * EMB + col);
        const float4 f1 = *(const float4*)(emb + (size_t)node * EMB + col + 4);
        v8h hv;
        hv[0] = (_Float16)f0.x; hv[1] = (_Float16)f0.y;
        hv[2] = (_Float16)f0.z; hv[3] = (_Float16)f0.w;
        hv[4] = (_Float16)f1.x; hv[5] = (_Float16)f1.y;
        hv[6] = (_Float16)f1.z; hv[7] = (_Float16)f1.w;
        *(v8h*)&S.XB[((size_t)kq * 32 + row) * 8] = hv;
    }
    __syncthreads();

    // ---- Witness 1: base(256) -> H(64) relu -> w1(64) sigmoid ----
    dense_mfma<256, 8, 64, 0>(ws + OFF_E1W1, e1_b1, S.XB, nullptr, S.H, wave, lane);
    __syncthreads();
    dense_mfma<64, 2, 64, 1>(ws + OFF_E1W2, e1_b2, S.H, nullptr, S.WIT, wave, lane);
    __syncthreads();

    // ---- Witness 2: [base|w1](320) -> H relu -> w2(128) sigmoid ----
    dense_mfma<320, 8, 64, 0>(ws + OFF_E2W1, e2_b1, S.XB, S.WIT, S.H, wave, lane);
    __syncthreads();
    dense_mfma<64, 2, 128, 1>(ws + OFF_E2W2, e2_b2, S.H, nullptr, S.WIT + 8 * 256, wave, lane);
    __syncthreads();

    // ---- Witness 3: [base|w2](384) -> H relu -> w3(256) sigmoid ----
    dense_mfma<384, 8, 64, 0>(ws + OFF_E3W1, e3_b1, S.XB, S.WIT + 8 * 256, S.H, wave, lane);
    __syncthreads();
    dense_mfma<64, 2, 256, 1>(ws + OFF_E3W2, e3_b2, S.H, nullptr, S.WIT + 24 * 256, wave, lane);
    __syncthreads();

    // ---- Tropical min-plus: CODE[m][o] = min_k (WIT[m][k] + T[o][k]) ----
    // wave -> (o-group of 16, row-half of 16); lane -> (o = l15, k-quarter = sub).
    // Per chunk: ONE fully-distinct 1KB weight load + 16 broadcast x-reads
    // + 128 pk-ops; cross-sub combine via shfl_xor.
    {
        const int g = wave >> 1;
        const int rh = wave & 1;
        const int l15 = lane & 15;
        const int sub = lane >> 4;
        const int o = g * 16 + l15;
        half2v acc[16];
        const half2v big = {(_Float16)60000.f, (_Float16)60000.f};
        #pragma unroll
        for (int r = 0; r < 16; ++r) acc[r] = big;
        const _Float16* Trow = ws + OFF_TROP + (size_t)o * 448 + sub * 112;
        #pragma unroll 2
        for (int c = 0; c < 14; ++c) {
            const float4 wr = *(const float4*)(Trow + c * 8);
            const half2v w0 = __builtin_bit_cast(half2v, wr.x);
            const half2v w1 = __builtin_bit_cast(half2v, wr.y);
            const half2v w2 = __builtin_bit_cast(half2v, wr.z);
            const half2v w3 = __builtin_bit_cast(half2v, wr.w);
            const int kq = sub * 14 + c;
            const _Float16* xb = &S.WIT[((size_t)kq * 32 + rh * 16) * 8];
            #pragma unroll
            for (int r = 0; r < 16; ++r) {
                const float4 xr = *(const float4*)(xb + r * 8);
                half2v t0 = __builtin_bit_cast(half2v, xr.x) + w0;
                half2v t1 = __builtin_bit_cast(half2v, xr.y) + w1;
                half2v t2 = __builtin_bit_cast(half2v, xr.z) + w2;
                half2v t3 = __builtin_bit_cast(half2v, xr.w) + w3;
                t0 = __builtin_elementwise_min(t0, t1);
                t2 = __builtin_elementwise_min(t2, t3);
                acc[r] = __builtin_elementwise_min(acc[r], __builtin_elementwise_min(t0, t2));
            }
        }
        #pragma unroll
        for (int r = 0; r < 16; ++r) {
            half2v v1 = __builtin_bit_cast(half2v,
                __shfl_xor(__builtin_bit_cast(int, acc[r]), 16, 64));
            acc[r] = __builtin_elementwise_min(acc[r], v1);
            half2v v2 = __builtin_bit_cast(half2v,
                __shfl_xor(__builtin_bit_cast(int, acc[r]), 32, 64));
            acc[r] = __builtin_elementwise_min(acc[r], v2);
        }
        if (sub == 0) {
            #pragma unroll
            for (int r = 0; r < 16; ++r) {
                const _Float16 lo = acc[r].x;
                const _Float16 hi = acc[r].y;
                S.CODE[((o >> 3) * 32 + rh * 16 + r) * 8 + (o & 7)] =
                    (lo < hi) ? lo : hi;
            }
        }
    }
    __syncthreads();

    // ---- Decoder 1: CODE(128) -> H(64) relu ----
    dense_mfma<128, 4, 64, 0>(ws + OFF_DW1, dec_b1, S.CODE, nullptr, S.H, wave, lane);
    __syncthreads();

    // ---- Decoder 2: H(64) -> scalar ----
    if (tid < TILE) {
        const int r = tid;
        float s = dec_b2[0];
        const _Float16* w2 = ws + OFF_DW2;
        #pragma unroll
        for (int c = 0; c < 8; ++c) {
            const float4 hr = *(const float4*)(&S.H[((size_t)c * 32 + r) * 8]);
            const float4 wr = *(const float4*)(w2 + c * 8);
            s = __builtin_amdgcn_fdot2(__builtin_bit_cast(half2v, hr.x), __builtin_bit_cast(half2v, wr.x), s, false);
            s = __builtin_amdgcn_fdot2(__builtin_bit_cast(half2v, hr.y), __builtin_bit_cast(half2v, wr.y), s, false);
            s = __builtin_amdgcn_fdot2(__builtin_bit_cast(half2v, hr.z), __builtin_bit_cast(half2v, wr.z), s, false);
            s = __builtin_amdgcn_fdot2(__builtin_bit_cast(half2v, hr.w), __builtin_bit_cast(half2v, wr.w), s, false);
        }
        out[row0 + r] = s;
    }
}

extern "C" void kernel_launch(void* const* d_in, const int* in_sizes, int n_in,
                              void* d_out, int out_size, void* d_ws, size_t ws_size,
                              hipStream_t stream) {
    const int*   u      = (const int*)d_in[0];
    const int*   v      = (const int*)d_in[1];
    const float* emb    = (const float*)d_in[2];
    const float* e1_w1  = (const float*)d_in[3];
    const float* e1_b1  = (const float*)d_in[4];
    const float* e1_w2  = (const float*)d_in[5];
    const float* e1_b2  = (const float*)d_in[6];
    const float* e2_w1  = (const float*)d_in[7];
    const float* e2_b1  = (const float*)d_in[8];
    const float* e2_w2  = (const float*)d_in[9];
    const float* e2_b2  = (const float*)d_in[10];
    const float* e3_w1  = (const float*)d_in[11];
    const float* e3_b1  = (const float*)d_in[12];
    const float* e3_w2  = (const float*)d_in[13];
    const float* e3_b2  = (const float*)d_in[14];
    const float* trop_w = (const float*)d_in[15];
    const float* dec_w1 = (const float*)d_in[16];
    const float* dec_b1 = (const float*)d_in[17];
    const float* dec_w2 = (const float*)d_in[18];
    const float* dec_b2 = (const float*)d_in[19];
    float* out = (float*)d_out;
    _Float16* ws = (_Float16*)d_ws;

    const int cvt_blocks = (W_TOTAL / 4 + 255) / 256;  // 153
    cvt_weights_kernel<<<cvt_blocks, 256, 0, stream>>>(
        e1_w1, e1_w2, e2_w1, e2_w2, e3_w1, e3_w2, trop_w, dec_w1, dec_w2, ws);

    tacit_fused_kernel<<<BATCH / TILE, NTHREADS, 0, stream>>>(
        u, v, emb,
        e1_b1, e1_b2, e2_b1, e2_b2, e3_b1, e3_b2, dec_b1, dec_b2,
        ws, out);
}